// Round 4
// baseline (767.764 us; speedup 1.0000x reference)
//
#include <hip/hip_runtime.h>
#include <cstdint>
#include <cstddef>

// SplineNet: 2x SplineConv (K=3, K=5) + ELU, MLP head. N=100K, E=1.6M, D=64, C=16.
//
// R4:
//  - permute (136us, line-thrash-bound) -> two-pass binned scatter:
//    bin_k (atomic bucket cursors -> adjacent positions -> full-line stores)
//    + binsort_k (per-bucket block, LDS cursors, localized writes).
//  - fp16 activations (xh, h) + fp16 agg: halves gather read/write traffic.
//  - GEMMs via v_mfma_f32_16x16x32_f16: 128x64 tile/block, 4 waves x (32x64),
//    fp32 accumulators, W pre-transposed to fp16 [n][k] once per call.
//
// ws layout: agg[N*320 h] 64MB | h[N*64 h] 12.8MB | xh[N*64 h] 12.8MB |
//            packed[E int2] 12.8MB | staging[E int2] 12.8MB | Wt1 32KB | Wt2 48KB |
//            rowptr[N+1] | deg[N] | partial[512] | bcur[NB]   ~= 117MB.

#define D_FEAT 64
#define AS_STRIDE 40   // halves; pad 32-k tile rows to break bank alignment

typedef _Float16 half8v __attribute__((ext_vector_type(8)));
typedef _Float16 half4v __attribute__((ext_vector_type(4)));
typedef float f32x4 __attribute__((ext_vector_type(4)));

__device__ __forceinline__ float elu_f(float x) {
    return x > 0.f ? x : expm1f(x);
}

// ---------- CSR build ----------

__global__ __launch_bounds__(256) void hist_k(
    const int* __restrict__ edst, unsigned int* __restrict__ deg, int E)
{
    int e = blockIdx.x * 256 + threadIdx.x;
    if (e < E) atomicAdd(&deg[edst[e]], 1u);
}

__global__ __launch_bounds__(256) void part_sum_k(
    const unsigned int* __restrict__ deg, unsigned int* __restrict__ partial, int N)
{
    __shared__ unsigned int wsum[4];
    int i = blockIdx.x * 256 + threadIdx.x;
    int lane = threadIdx.x & 63, wid = threadIdx.x >> 6;
    unsigned int v = (i < N) ? deg[i] : 0u;
    #pragma unroll
    for (int off = 32; off; off >>= 1) v += __shfl_xor(v, off);
    if (lane == 0) wsum[wid] = v;
    __syncthreads();
    if (threadIdx.x == 0)
        partial[blockIdx.x] = wsum[0] + wsum[1] + wsum[2] + wsum[3];
}

__global__ __launch_bounds__(512) void part_scan_k(
    unsigned int* __restrict__ partial, int nb)
{
    __shared__ unsigned int wsum[8];
    int t = threadIdx.x, lane = t & 63, wid = t >> 6;
    unsigned int v = (t < nb) ? partial[t] : 0u;
    unsigned int orig = v;
    #pragma unroll
    for (int off = 1; off < 64; off <<= 1) {
        unsigned int s = __shfl_up(v, off);
        if (lane >= off) v += s;
    }
    if (lane == 63) wsum[wid] = v;
    __syncthreads();
    unsigned int add = 0;
    for (int i = 0; i < wid; ++i) add += wsum[i];
    if (t < nb) partial[t] = v + add - orig;
}

// writes rowptr + per-bucket start cursors (bucket = 128 nodes)
__global__ __launch_bounds__(256) void scan_write_k(
    const unsigned int* __restrict__ deg, const unsigned int* __restrict__ partial,
    unsigned int* __restrict__ rowptr, unsigned int* __restrict__ bcur, int N, int E)
{
    __shared__ unsigned int wsum[4];
    int i = blockIdx.x * 256 + threadIdx.x;
    int lane = threadIdx.x & 63, wid = threadIdx.x >> 6;
    unsigned int v = (i < N) ? deg[i] : 0u;
    unsigned int orig = v;
    #pragma unroll
    for (int off = 1; off < 64; off <<= 1) {
        unsigned int s = __shfl_up(v, off);
        if (lane >= off) v += s;
    }
    if (lane == 63) wsum[wid] = v;
    __syncthreads();
    unsigned int add = partial[blockIdx.x];
    for (int w = 0; w < wid; ++w) add += wsum[w];
    unsigned int excl = add + v - orig;
    if (i < N) {
        rowptr[i] = excl;
        if ((i & 127) == 0) bcur[i >> 7] = excl;
    }
    if (blockIdx.x == 0 && threadIdx.x == 0) rowptr[N] = (unsigned int)E;
}

// pass A: bin edges into 128-node dst buckets. Concurrent atomics on one
// bucket yield adjacent positions -> stores fill whole lines.
__global__ __launch_bounds__(256) void bin_k(
    const int* __restrict__ esrc, const int* __restrict__ edst,
    const float* __restrict__ attr, unsigned int* __restrict__ bcur,
    int2* __restrict__ staging, int E)
{
    int e = blockIdx.x * 256 + threadIdx.x;
    if (e < E) {
        int d = edst[e];
        unsigned int pos = atomicAdd(&bcur[d >> 7], 1u);
        staging[pos] = make_int2(esrc[e] | ((d & 127) << 17), __float_as_int(attr[e]));
    }
}

// pass B: one block per bucket; coalesced staging read, LDS cursors,
// final writes localized to the bucket's contiguous packed region.
__global__ __launch_bounds__(256) void binsort_k(
    const int2* __restrict__ staging, const unsigned int* __restrict__ rowptr,
    int2* __restrict__ packed, int N)
{
    __shared__ unsigned int cur[128];
    int node0 = blockIdx.x << 7;
    int t = threadIdx.x;
    int hi = node0 + 128; if (hi > N) hi = N;
    if (t < 128 && node0 + t < N) cur[t] = rowptr[node0 + t];
    __syncthreads();
    unsigned int start = rowptr[node0];
    unsigned int end = rowptr[hi];
    for (unsigned int i = start + t; i < end; i += 256) {
        int2 rec = staging[i];
        int dOff = (rec.x >> 17) & 127;
        unsigned int pos = atomicAdd(&cur[dOff], 1u);
        packed[pos] = make_int2(rec.x & 0x1FFFF, rec.y);
    }
}

// ---------- fp16 conversions (once per call) ----------

__global__ __launch_bounds__(256) void cvt_x_k(
    const float* __restrict__ x, _Float16* __restrict__ xh, int total4)
{
    int i = blockIdx.x * 256 + threadIdx.x;
    if (i < total4) {
        float4 v = ((const float4*)x)[i];
        half4v hv = { (_Float16)v.x, (_Float16)v.y, (_Float16)v.z, (_Float16)v.w };
        ((half4v*)xh)[i] = hv;
    }
}

// Wt[n][k] = fp16( cat(W, root)[k][n] ) — B^T layout for the MFMA B-fragment.
__global__ __launch_bounds__(256) void prep_w_k(
    const float* __restrict__ W1, const float* __restrict__ root1,
    const float* __restrict__ W2, const float* __restrict__ root2,
    _Float16* __restrict__ Wt1, _Float16* __restrict__ Wt2)
{
    int i = blockIdx.x * 256 + threadIdx.x;
    if (i < 64 * 256) {
        int n = i >> 8, k = i & 255;
        float v = (k < 192) ? W1[k * 64 + n] : root1[(k - 192) * 64 + n];
        Wt1[n * 256 + k] = (_Float16)v;
    } else if (i < 64 * 256 + 64 * 384) {
        int j = i - 64 * 256;
        int n = j / 384, k = j % 384;
        float v = (k < 320) ? W2[k * 64 + n] : root2[(k - 320) * 64 + n];
        Wt2[n * 384 + k] = (_Float16)v;
    }
}

// ---------- gather: agg[n][k][:] = (1/deg) * sum_e coeff_k(e) * x[src(e)][:]
// wave = node; lane = (edge-slot 0..3) x (16 half4 columns). fp16 in/out, fp32 acc.

template<int K>
__global__ __launch_bounds__(256) void gather_k(
    const _Float16* __restrict__ xin,
    const int2* __restrict__ packed,
    const unsigned int* __restrict__ rowptr,
    _Float16* __restrict__ agg, int N)
{
    int n = blockIdx.x * 4 + (threadIdx.x >> 6);
    int lane = threadIdx.x & 63;
    if (n >= N) return;
    int sub = lane >> 4;
    int col = (lane & 15) << 2;
    unsigned int s0 = rowptr[n], s1 = rowptr[n + 1];
    float acc[K][4];
    #pragma unroll
    for (int k = 0; k < K; ++k)
        #pragma unroll
        for (int j = 0; j < 4; ++j) acc[k][j] = 0.f;
    for (unsigned int e = s0; e < s1; e += 4) {
        unsigned int ee = e + (unsigned int)sub;
        bool valid = ee < s1;
        int2 pe = packed[valid ? ee : s1 - 1];
        float v = __int_as_float(pe.y) * (float)(K - 1);
        half4v hv = *(const half4v*)(xin + (size_t)pe.x * D_FEAT + col);
        float xv[4] = { (float)hv[0], (float)hv[1], (float)hv[2], (float)hv[3] };
        #pragma unroll
        for (int k = 0; k < K; ++k) {
            float w = fmaxf(1.f - fabsf(v - (float)k), 0.f);
            w = valid ? w : 0.f;
            #pragma unroll
            for (int j = 0; j < 4; ++j) acc[k][j] = fmaf(xv[j], w, acc[k][j]);
        }
    }
    float inv = 1.f / fmaxf((float)(s1 - s0), 1.f);
    #pragma unroll
    for (int k = 0; k < K; ++k) {
        float a[4];
        #pragma unroll
        for (int j = 0; j < 4; ++j) {
            a[j] = acc[k][j];
            a[j] += __shfl_xor(a[j], 16);
            a[j] += __shfl_xor(a[j], 32);
        }
        if (sub == 0) {
            half4v o = { (_Float16)(a[0] * inv), (_Float16)(a[1] * inv),
                         (_Float16)(a[2] * inv), (_Float16)(a[3] * inv) };
            *(half4v*)(agg + ((size_t)n * K + k) * D_FEAT + col) = o;
        }
    }
}

// ---------- MFMA GEMM: outh = elu_f16( [A | X] @ Wt^T + bias ) ----------
// A: [N][lenA] fp16 (agg), X: [N][64] fp16, Wt: [64][Kd] fp16 (pre-transposed),
// Kd = lenA+64. 128x64 tile per 256-thread block; wave w = rows w*32..w*32+31.
// Frag layouts (guide §3, HW-verified): A[m=lane&15][k=q*8+j], B[k=q*8+j][n=lane&15],
// C/D: col=lane&15, row=q*4+reg.

__global__ __launch_bounds__(256) void gemm_mfma(
    const _Float16* __restrict__ A, int lenA,
    const _Float16* __restrict__ X,
    const _Float16* __restrict__ Wt,
    const float* __restrict__ bias,
    _Float16* __restrict__ outh, int N)
{
    __shared__ _Float16 As[128 * AS_STRIDE];
    __shared__ _Float16 Bs[64 * AS_STRIDE];
    int t = threadIdx.x;
    int row0 = blockIdx.x * 128;
    int Kd = lenA + D_FEAT;
    int w = t >> 6, lane = t & 63;
    int m16 = lane & 15, q = lane >> 4;

    f32x4 acc[2][4];
    #pragma unroll
    for (int rf = 0; rf < 2; ++rf)
        #pragma unroll
        for (int c = 0; c < 4; ++c) acc[rf][c] = (f32x4){0.f, 0.f, 0.f, 0.f};

    int srow = t >> 1;             // 0..127
    int skh  = (t & 1) * 16;       // halves 0 or 16
    int bn   = t >> 2;             // 0..63
    int bkq  = (t & 3) * 8;

    int grow = row0 + srow; if (grow >= N) grow = N - 1;
    const _Float16* arowA = A + (size_t)grow * lenA;
    const _Float16* arowX = X + (size_t)grow * D_FEAT;

    for (int kk = 0; kk < Kd; kk += 32) {
        const _Float16* src = (kk < lenA) ? (arowA + kk + skh)
                                          : (arowX + (kk - lenA) + skh);
        half8v a0 = *(const half8v*)(src);
        half8v a1 = *(const half8v*)(src + 8);
        half8v b0 = *(const half8v*)(Wt + (size_t)bn * Kd + kk + bkq);
        __syncthreads();
        *(half8v*)(&As[srow * AS_STRIDE + skh]) = a0;
        *(half8v*)(&As[srow * AS_STRIDE + skh + 8]) = a1;
        *(half8v*)(&Bs[bn * AS_STRIDE + bkq]) = b0;
        __syncthreads();
        half8v af0 = *(const half8v*)(&As[(w * 32 + m16) * AS_STRIDE + q * 8]);
        half8v af1 = *(const half8v*)(&As[(w * 32 + 16 + m16) * AS_STRIDE + q * 8]);
        #pragma unroll
        for (int c = 0; c < 4; ++c) {
            half8v bf = *(const half8v*)(&Bs[(c * 16 + m16) * AS_STRIDE + q * 8]);
            acc[0][c] = __builtin_amdgcn_mfma_f32_16x16x32_f16(af0, bf, acc[0][c], 0, 0, 0);
            acc[1][c] = __builtin_amdgcn_mfma_f32_16x16x32_f16(af1, bf, acc[1][c], 0, 0, 0);
        }
    }

    #pragma unroll
    for (int rf = 0; rf < 2; ++rf)
        #pragma unroll
        for (int c = 0; c < 4; ++c) {
            int colg = c * 16 + m16;
            float bb = bias[colg];
            #pragma unroll
            for (int r = 0; r < 4; ++r) {
                int rowg = row0 + w * 32 + rf * 16 + q * 4 + r;
                if (rowg < N) {
                    float vv = elu_f(acc[rf][c][r] + bb);
                    outh[(size_t)rowg * D_FEAT + colg] = (_Float16)vv;
                }
            }
        }
}

// ---------- fused MLP head (fp16 input, fp32 math) ----------

__global__ __launch_bounds__(256) void mlp_tile(
    const _Float16* __restrict__ X,   // h [N,64] fp16
    const float* __restrict__ Wm1,    // [64][64]
    const float* __restrict__ bm1,    // [64]
    const float* __restrict__ Wm2,    // [64][16]
    const float* __restrict__ bm2,    // [16]
    float* __restrict__ out, int N)
{
    __shared__ float As[16][68];
    __shared__ float Bs[16][68];
    __shared__ float Hs[64][68];
    int t = threadIdx.x;
    int tx = t & 15, ty = t >> 4;
    int row0 = blockIdx.x * 64;
    float acc[4][4];
    #pragma unroll
    for (int i = 0; i < 4; ++i)
        #pragma unroll
        for (int j = 0; j < 4; ++j) acc[i][j] = 0.f;

    int lrow = t >> 2;
    int lkq  = (t & 3) << 2;
    int bkr  = t >> 4;
    int bcol = (t & 15) << 2;

    for (int kk = 0; kk < D_FEAT; kk += 16) {
        int gr = row0 + lrow; if (gr >= N) gr = N - 1;
        half4v hv = *(const half4v*)(X + (size_t)gr * D_FEAT + kk + lkq);
        float4 b4 = *(const float4*)(Wm1 + (size_t)(kk + bkr) * D_FEAT + bcol);
        __syncthreads();
        As[lkq + 0][lrow] = (float)hv[0];
        As[lkq + 1][lrow] = (float)hv[1];
        As[lkq + 2][lrow] = (float)hv[2];
        As[lkq + 3][lrow] = (float)hv[3];
        *(float4*)(&Bs[bkr][bcol]) = b4;
        __syncthreads();
        #pragma unroll
        for (int k = 0; k < 16; ++k) {
            float4 av = *(const float4*)(&As[k][ty << 2]);
            float4 bv = *(const float4*)(&Bs[k][tx << 2]);
            acc[0][0] = fmaf(av.x, bv.x, acc[0][0]);
            acc[0][1] = fmaf(av.x, bv.y, acc[0][1]);
            acc[0][2] = fmaf(av.x, bv.z, acc[0][2]);
            acc[0][3] = fmaf(av.x, bv.w, acc[0][3]);
            acc[1][0] = fmaf(av.y, bv.x, acc[1][0]);
            acc[1][1] = fmaf(av.y, bv.y, acc[1][1]);
            acc[1][2] = fmaf(av.y, bv.z, acc[1][2]);
            acc[1][3] = fmaf(av.y, bv.w, acc[1][3]);
            acc[2][0] = fmaf(av.z, bv.x, acc[2][0]);
            acc[2][1] = fmaf(av.z, bv.y, acc[2][1]);
            acc[2][2] = fmaf(av.z, bv.z, acc[2][2]);
            acc[2][3] = fmaf(av.z, bv.w, acc[2][3]);
            acc[3][0] = fmaf(av.w, bv.x, acc[3][0]);
            acc[3][1] = fmaf(av.w, bv.y, acc[3][1]);
            acc[3][2] = fmaf(av.w, bv.z, acc[3][2]);
            acc[3][3] = fmaf(av.w, bv.w, acc[3][3]);
        }
    }

    float4 bv4 = *(const float4*)(bm1 + (tx << 2));
    #pragma unroll
    for (int i = 0; i < 4; ++i) {
        float4 o;
        o.x = fmaxf(acc[i][0] + bv4.x, 0.f);
        o.y = fmaxf(acc[i][1] + bv4.y, 0.f);
        o.z = fmaxf(acc[i][2] + bv4.z, 0.f);
        o.w = fmaxf(acc[i][3] + bv4.w, 0.f);
        *(float4*)(&Hs[(ty << 2) + i][tx << 2]) = o;
    }
    __syncthreads();

    int r = t >> 2;
    int cg = (t & 3) << 2;
    float4 o2 = make_float4(0.f, 0.f, 0.f, 0.f);
    #pragma unroll 8
    for (int k = 0; k < D_FEAT; ++k) {
        float hk = Hs[r][k];
        float4 w4 = *(const float4*)(Wm2 + k * 16 + cg);
        o2.x = fmaf(hk, w4.x, o2.x);
        o2.y = fmaf(hk, w4.y, o2.y);
        o2.z = fmaf(hk, w4.z, o2.z);
        o2.w = fmaf(hk, w4.w, o2.w);
    }
    int gr = row0 + r;
    if (gr < N) {
        float4 b2 = *(const float4*)(bm2 + cg);
        float4 o;
        o.x = fmaxf(o2.x + b2.x, 0.f);
        o.y = fmaxf(o2.y + b2.y, 0.f);
        o.z = fmaxf(o2.z + b2.z, 0.f);
        o.w = fmaxf(o2.w + b2.w, 0.f);
        *(float4*)(out + (size_t)gr * 16 + cg) = o;
    }
}

extern "C" void kernel_launch(void* const* d_in, const int* in_sizes, int n_in,
                              void* d_out, int out_size, void* d_ws, size_t ws_size,
                              hipStream_t stream)
{
    const float* x     = (const float*)d_in[0];
    const int*   eidx  = (const int*)d_in[1];
    const float* attr  = (const float*)d_in[2];
    const float* W1    = (const float*)d_in[3];
    const float* root1 = (const float*)d_in[4];
    const float* b1    = (const float*)d_in[5];
    const float* W2    = (const float*)d_in[6];
    const float* root2 = (const float*)d_in[7];
    const float* b2    = (const float*)d_in[8];
    const float* Wm1   = (const float*)d_in[9];
    const float* bm1   = (const float*)d_in[10];
    const float* Wm2   = (const float*)d_in[11];
    const float* bm2   = (const float*)d_in[12];
    float* out = (float*)d_out;

    int N = in_sizes[0] / D_FEAT;
    int E = in_sizes[1] / 2;
    const int* esrc = eidx;
    const int* edst = eidx + E;
    int NB = (N + 127) >> 7;

    _Float16* agg = (_Float16*)d_ws;
    _Float16* h   = agg + (size_t)N * 5 * D_FEAT;
    _Float16* xh  = h + (size_t)N * D_FEAT;
    int2* packed  = (int2*)(xh + (size_t)N * D_FEAT);
    int2* staging = packed + E;
    _Float16* Wt1 = (_Float16*)(staging + E);
    _Float16* Wt2 = Wt1 + 64 * 256;
    unsigned int* rowptr  = (unsigned int*)(Wt2 + 64 * 384);
    unsigned int* deg     = rowptr + (N + 1);
    unsigned int* partial = deg + N;
    unsigned int* bcur    = partial + 512;

    dim3 blk(256);
    int nb = (N + 255) / 256;
    dim3 grid_e((E + 255) / 256);
    dim3 grid_s(nb);
    dim3 grid_w((N + 3) / 4);
    dim3 grid_g64((N + 63) / 64);
    dim3 grid_g128((N + 127) / 128);

    // CSR build (two-pass binned scatter)
    hipMemsetAsync(deg, 0, (size_t)N * sizeof(unsigned int), stream);
    hist_k<<<grid_e, blk, 0, stream>>>(edst, deg, E);
    part_sum_k<<<grid_s, blk, 0, stream>>>(deg, partial, N);
    part_scan_k<<<1, 512, 0, stream>>>(partial, nb);
    scan_write_k<<<grid_s, blk, 0, stream>>>(deg, partial, rowptr, bcur, N, E);
    bin_k<<<grid_e, blk, 0, stream>>>(esrc, edst, attr, bcur, staging, E);
    binsort_k<<<dim3(NB), blk, 0, stream>>>(staging, rowptr, packed, N);

    // fp16 prep
    cvt_x_k<<<dim3((N * D_FEAT / 4 + 255) / 256), blk, 0, stream>>>(x, xh, N * D_FEAT / 4);
    prep_w_k<<<dim3(160), blk, 0, stream>>>(W1, root1, W2, root2, Wt1, Wt2);

    // conv1: K=3
    gather_k<3><<<grid_w, blk, 0, stream>>>(xh, packed, rowptr, agg, N);
    gemm_mfma<<<grid_g128, blk, 0, stream>>>(agg, 3 * D_FEAT, xh, Wt1, b1, h, N);

    // conv2: K=5 (gemm reads/writes h in place — per-block row ownership)
    gather_k<5><<<grid_w, blk, 0, stream>>>(h, packed, rowptr, agg, N);
    gemm_mfma<<<grid_g128, blk, 0, stream>>>(agg, 5 * D_FEAT, h, Wt2, b2, h, N);

    // MLP head
    mlp_tile<<<grid_g64, blk, 0, stream>>>(h, Wm1, bm1, Wm2, bm2, out, N);
}

// Round 5
// 378.523 us; speedup vs baseline: 2.0283x; 2.0283x over previous
//
#include <hip/hip_runtime.h>
#include <cstdint>
#include <cstddef>

// SplineNet: 2x SplineConv (K=3, K=5) + ELU, MLP head. N=100K, E=1.6M, D=64, C=16.
//
// R5: CSR build rebuilt as an atomic-free partition sort:
//   count_k (LDS-private bucket hist per edge-chunk) -> flat 3-pass scan over
//   counts[bucket][block] -> place_k (LDS cursors, clustered stores into
//   bucket-grouped staging) -> binsort_k (per-bucket LDS node hist + scan;
//   emits rowptr AND node-grouped packed). Zero global atomics anywhere.
//   R4's bin_k died on same-line atomic contention (376us, VALUBusy 0.16%).
//
// ws layout: agg[N*320 h] 64MB | h[N*64 h] 12.8MB | xh[N*64 h] 12.8MB |
//   packed[E int2] 12.8MB | staging[E int2] 12.8MB | Wt1 32KB | Wt2 48KB |
//   counts[NBUCKET*128 u32] 400KB | partial[512] | rowptr[N+1]  ~= 116MB.

#define D_FEAT 64
#define AS_STRIDE 40   // halves; pad 32-k tile rows to break bank alignment
#define NB_MAX 1024    // max dst-buckets (128 nodes each) -> N <= 131072
#define PART_B 128     // partition blocks (edge chunks)

typedef _Float16 half8v __attribute__((ext_vector_type(8)));
typedef _Float16 half4v __attribute__((ext_vector_type(4)));
typedef float f32x4 __attribute__((ext_vector_type(4)));

__device__ __forceinline__ float elu_f(float x) {
    return x > 0.f ? x : expm1f(x);
}

// ---------- partition sort (atomic-free CSR build) ----------

// pass 1: per-chunk LDS histogram over dst-buckets (bucket = dst>>7)
__global__ __launch_bounds__(256) void count_k(
    const int* __restrict__ edst, unsigned int* __restrict__ counts,
    int E, int chunk, int NBUCKET)
{
    __shared__ unsigned int hist[NB_MAX];
    int t = threadIdx.x;
    for (int b = t; b < NBUCKET; b += 256) hist[b] = 0u;
    __syncthreads();
    int e0 = blockIdx.x * chunk;
    int e1 = e0 + chunk; if (e1 > E) e1 = E;
    for (int e = e0 + t; e < e1; e += 256)
        atomicAdd(&hist[edst[e] >> 7], 1u);
    __syncthreads();
    for (int b = t; b < NBUCKET; b += 256)
        counts[(size_t)b * PART_B + blockIdx.x] = hist[b];
}

// flat multi-block exclusive scan over counts[L], L = NBUCKET*PART_B
__global__ __launch_bounds__(256) void psum_k(
    const unsigned int* __restrict__ data, unsigned int* __restrict__ partial, int L)
{
    __shared__ unsigned int wsum[4];
    int i = blockIdx.x * 256 + threadIdx.x;
    int lane = threadIdx.x & 63, wid = threadIdx.x >> 6;
    unsigned int v = (i < L) ? data[i] : 0u;
    #pragma unroll
    for (int off = 32; off; off >>= 1) v += __shfl_xor(v, off);
    if (lane == 0) wsum[wid] = v;
    __syncthreads();
    if (threadIdx.x == 0)
        partial[blockIdx.x] = wsum[0] + wsum[1] + wsum[2] + wsum[3];
}

__global__ __launch_bounds__(512) void pscan_k(
    unsigned int* __restrict__ partial, int nb)
{
    __shared__ unsigned int wsum[8];
    int t = threadIdx.x, lane = t & 63, wid = t >> 6;
    unsigned int v = (t < nb) ? partial[t] : 0u;
    unsigned int orig = v;
    #pragma unroll
    for (int off = 1; off < 64; off <<= 1) {
        unsigned int s = __shfl_up(v, off);
        if (lane >= off) v += s;
    }
    if (lane == 63) wsum[wid] = v;
    __syncthreads();
    unsigned int add = 0;
    for (int i = 0; i < wid; ++i) add += wsum[i];
    if (t < nb) partial[t] = v + add - orig;
}

__global__ __launch_bounds__(256) void pwrite_k(
    unsigned int* __restrict__ data, const unsigned int* __restrict__ partial, int L)
{
    __shared__ unsigned int wsum[4];
    int i = blockIdx.x * 256 + threadIdx.x;
    int lane = threadIdx.x & 63, wid = threadIdx.x >> 6;
    unsigned int v = (i < L) ? data[i] : 0u;
    unsigned int orig = v;
    #pragma unroll
    for (int off = 1; off < 64; off <<= 1) {
        unsigned int s = __shfl_up(v, off);
        if (lane >= off) v += s;
    }
    if (lane == 63) wsum[wid] = v;
    __syncthreads();
    unsigned int add = partial[blockIdx.x];
    for (int w = 0; w < wid; ++w) add += wsum[w];
    if (i < L) data[i] = add + v - orig;
}

// pass 2: re-read chunk, place records into bucket-grouped staging via LDS cursors
__global__ __launch_bounds__(256) void place_k(
    const int* __restrict__ esrc, const int* __restrict__ edst,
    const float* __restrict__ attr, const unsigned int* __restrict__ off,
    int2* __restrict__ staging, int E, int chunk, int NBUCKET)
{
    __shared__ unsigned int cur[NB_MAX];
    int t = threadIdx.x;
    for (int b = t; b < NBUCKET; b += 256)
        cur[b] = off[(size_t)b * PART_B + blockIdx.x];
    __syncthreads();
    int e0 = blockIdx.x * chunk;
    int e1 = e0 + chunk; if (e1 > E) e1 = E;
    for (int e = e0 + t; e < e1; e += 256) {
        int d = edst[e];
        unsigned int pos = atomicAdd(&cur[d >> 7], 1u);   // LDS atomic
        staging[pos] = make_int2(esrc[e] | ((d & 127) << 17), __float_as_int(attr[e]));
    }
}

// pass 3: one block per bucket; LDS node-hist + scan -> rowptr; place node-grouped
__global__ __launch_bounds__(256) void binsort_k(
    const int2* __restrict__ staging, const unsigned int* __restrict__ off,
    unsigned int* __restrict__ rowptr, int2* __restrict__ packed,
    int N, int E, int NBUCKET)
{
    __shared__ unsigned int nh[128];
    __shared__ unsigned int cur[128];
    __shared__ unsigned int wtot[2];
    int bkt = blockIdx.x;
    int t = threadIdx.x;
    int node0 = bkt << 7;
    unsigned int start = off[(size_t)bkt * PART_B];
    unsigned int end = (bkt + 1 < NBUCKET) ? off[(size_t)(bkt + 1) * PART_B]
                                           : (unsigned int)E;
    if (t < 128) nh[t] = 0u;
    __syncthreads();
    for (unsigned int i = start + t; i < end; i += 256)
        atomicAdd(&nh[(staging[i].x >> 17) & 127], 1u);
    __syncthreads();
    if (t < 128) {                      // waves 0,1 fully active: shfl safe
        int lane = t & 63;
        unsigned int v = nh[t], orig = v;
        #pragma unroll
        for (int o = 1; o < 64; o <<= 1) {
            unsigned int s = __shfl_up(v, o);
            if (lane >= o) v += s;
        }
        if (lane == 63) wtot[t >> 6] = v;
        nh[t] = v - orig;               // exclusive within wave
    }
    __syncthreads();
    if (t < 128) {
        unsigned int add = (t >= 64) ? wtot[0] : 0u;
        unsigned int base = start + add + nh[t];
        cur[t] = base;
        int node = node0 + t;
        if (node < N) rowptr[node] = base;
    }
    if (bkt == NBUCKET - 1 && t == 0) rowptr[N] = (unsigned int)E;
    __syncthreads();
    for (unsigned int i = start + t; i < end; i += 256) {
        int2 r = staging[i];
        unsigned int pos = atomicAdd(&cur[(r.x >> 17) & 127], 1u);
        packed[pos] = make_int2(r.x & 0x1FFFF, r.y);
    }
}

// ---------- fp16 conversions (once per call) ----------

__global__ __launch_bounds__(256) void cvt_x_k(
    const float* __restrict__ x, _Float16* __restrict__ xh, int total4)
{
    int i = blockIdx.x * 256 + threadIdx.x;
    if (i < total4) {
        float4 v = ((const float4*)x)[i];
        half4v hv = { (_Float16)v.x, (_Float16)v.y, (_Float16)v.z, (_Float16)v.w };
        ((half4v*)xh)[i] = hv;
    }
}

// Wt[n][k] = fp16( cat(W, root)[k][n] ) — B^T layout for the MFMA B-fragment.
__global__ __launch_bounds__(256) void prep_w_k(
    const float* __restrict__ W1, const float* __restrict__ root1,
    const float* __restrict__ W2, const float* __restrict__ root2,
    _Float16* __restrict__ Wt1, _Float16* __restrict__ Wt2)
{
    int i = blockIdx.x * 256 + threadIdx.x;
    if (i < 64 * 256) {
        int n = i >> 8, k = i & 255;
        float v = (k < 192) ? W1[k * 64 + n] : root1[(k - 192) * 64 + n];
        Wt1[n * 256 + k] = (_Float16)v;
    } else if (i < 64 * 256 + 64 * 384) {
        int j = i - 64 * 256;
        int n = j / 384, k = j % 384;
        float v = (k < 320) ? W2[k * 64 + n] : root2[(k - 320) * 64 + n];
        Wt2[n * 384 + k] = (_Float16)v;
    }
}

// ---------- gather: agg[n][k][:] = (1/deg) * sum_e coeff_k(e) * x[src(e)][:]
// wave = node; lane = (edge-slot 0..3) x (16 half4 columns). fp16 in/out, fp32 acc.

template<int K>
__global__ __launch_bounds__(256) void gather_k(
    const _Float16* __restrict__ xin,
    const int2* __restrict__ packed,
    const unsigned int* __restrict__ rowptr,
    _Float16* __restrict__ agg, int N)
{
    int n = blockIdx.x * 4 + (threadIdx.x >> 6);
    int lane = threadIdx.x & 63;
    if (n >= N) return;
    int sub = lane >> 4;
    int col = (lane & 15) << 2;
    unsigned int s0 = rowptr[n], s1 = rowptr[n + 1];
    float acc[K][4];
    #pragma unroll
    for (int k = 0; k < K; ++k)
        #pragma unroll
        for (int j = 0; j < 4; ++j) acc[k][j] = 0.f;
    for (unsigned int e = s0; e < s1; e += 4) {
        unsigned int ee = e + (unsigned int)sub;
        bool valid = ee < s1;
        int2 pe = packed[valid ? ee : s1 - 1];
        float v = __int_as_float(pe.y) * (float)(K - 1);
        half4v hv = *(const half4v*)(xin + (size_t)pe.x * D_FEAT + col);
        float xv[4] = { (float)hv[0], (float)hv[1], (float)hv[2], (float)hv[3] };
        #pragma unroll
        for (int k = 0; k < K; ++k) {
            float w = fmaxf(1.f - fabsf(v - (float)k), 0.f);
            w = valid ? w : 0.f;
            #pragma unroll
            for (int j = 0; j < 4; ++j) acc[k][j] = fmaf(xv[j], w, acc[k][j]);
        }
    }
    float inv = 1.f / fmaxf((float)(s1 - s0), 1.f);
    #pragma unroll
    for (int k = 0; k < K; ++k) {
        float a[4];
        #pragma unroll
        for (int j = 0; j < 4; ++j) {
            a[j] = acc[k][j];
            a[j] += __shfl_xor(a[j], 16);
            a[j] += __shfl_xor(a[j], 32);
        }
        if (sub == 0) {
            half4v o = { (_Float16)(a[0] * inv), (_Float16)(a[1] * inv),
                         (_Float16)(a[2] * inv), (_Float16)(a[3] * inv) };
            *(half4v*)(agg + ((size_t)n * K + k) * D_FEAT + col) = o;
        }
    }
}

// ---------- MFMA GEMM: outh = elu_f16( [A | X] @ Wt^T + bias ) ----------
// 128x64 tile per 256-thread block; wave w = rows w*32..w*32+31.
// Frag layouts: A[m=lane&15][k=q*8+j], B[k=q*8+j][n=lane&15], C/D col=lane&15,row=q*4+reg.

__global__ __launch_bounds__(256) void gemm_mfma(
    const _Float16* __restrict__ A, int lenA,
    const _Float16* __restrict__ X,
    const _Float16* __restrict__ Wt,
    const float* __restrict__ bias,
    _Float16* __restrict__ outh, int N)
{
    __shared__ _Float16 As[128 * AS_STRIDE];
    __shared__ _Float16 Bs[64 * AS_STRIDE];
    int t = threadIdx.x;
    int row0 = blockIdx.x * 128;
    int Kd = lenA + D_FEAT;
    int w = t >> 6, lane = t & 63;
    int m16 = lane & 15, q = lane >> 4;

    f32x4 acc[2][4];
    #pragma unroll
    for (int rf = 0; rf < 2; ++rf)
        #pragma unroll
        for (int c = 0; c < 4; ++c) acc[rf][c] = (f32x4){0.f, 0.f, 0.f, 0.f};

    int srow = t >> 1;
    int skh  = (t & 1) * 16;
    int bn   = t >> 2;
    int bkq  = (t & 3) * 8;

    int grow = row0 + srow; if (grow >= N) grow = N - 1;
    const _Float16* arowA = A + (size_t)grow * lenA;
    const _Float16* arowX = X + (size_t)grow * D_FEAT;

    for (int kk = 0; kk < Kd; kk += 32) {
        const _Float16* src = (kk < lenA) ? (arowA + kk + skh)
                                          : (arowX + (kk - lenA) + skh);
        half8v a0 = *(const half8v*)(src);
        half8v a1 = *(const half8v*)(src + 8);
        half8v b0 = *(const half8v*)(Wt + (size_t)bn * Kd + kk + bkq);
        __syncthreads();
        *(half8v*)(&As[srow * AS_STRIDE + skh]) = a0;
        *(half8v*)(&As[srow * AS_STRIDE + skh + 8]) = a1;
        *(half8v*)(&Bs[bn * AS_STRIDE + bkq]) = b0;
        __syncthreads();
        half8v af0 = *(const half8v*)(&As[(w * 32 + m16) * AS_STRIDE + q * 8]);
        half8v af1 = *(const half8v*)(&As[(w * 32 + 16 + m16) * AS_STRIDE + q * 8]);
        #pragma unroll
        for (int c = 0; c < 4; ++c) {
            half8v bf = *(const half8v*)(&Bs[(c * 16 + m16) * AS_STRIDE + q * 8]);
            acc[0][c] = __builtin_amdgcn_mfma_f32_16x16x32_f16(af0, bf, acc[0][c], 0, 0, 0);
            acc[1][c] = __builtin_amdgcn_mfma_f32_16x16x32_f16(af1, bf, acc[1][c], 0, 0, 0);
        }
    }

    #pragma unroll
    for (int rf = 0; rf < 2; ++rf)
        #pragma unroll
        for (int c = 0; c < 4; ++c) {
            int colg = c * 16 + m16;
            float bb = bias[colg];
            #pragma unroll
            for (int r = 0; r < 4; ++r) {
                int rowg = row0 + w * 32 + rf * 16 + q * 4 + r;
                if (rowg < N) {
                    float vv = elu_f(acc[rf][c][r] + bb);
                    outh[(size_t)rowg * D_FEAT + colg] = (_Float16)vv;
                }
            }
        }
}

// ---------- fused MLP head (fp16 input, fp32 math) ----------

__global__ __launch_bounds__(256) void mlp_tile(
    const _Float16* __restrict__ X,
    const float* __restrict__ Wm1,
    const float* __restrict__ bm1,
    const float* __restrict__ Wm2,
    const float* __restrict__ bm2,
    float* __restrict__ out, int N)
{
    __shared__ float As[16][68];
    __shared__ float Bs[16][68];
    __shared__ float Hs[64][68];
    int t = threadIdx.x;
    int tx = t & 15, ty = t >> 4;
    int row0 = blockIdx.x * 64;
    float acc[4][4];
    #pragma unroll
    for (int i = 0; i < 4; ++i)
        #pragma unroll
        for (int j = 0; j < 4; ++j) acc[i][j] = 0.f;

    int lrow = t >> 2;
    int lkq  = (t & 3) << 2;
    int bkr  = t >> 4;
    int bcol = (t & 15) << 2;

    for (int kk = 0; kk < D_FEAT; kk += 16) {
        int gr = row0 + lrow; if (gr >= N) gr = N - 1;
        half4v hv = *(const half4v*)(X + (size_t)gr * D_FEAT + kk + lkq);
        float4 b4 = *(const float4*)(Wm1 + (size_t)(kk + bkr) * D_FEAT + bcol);
        __syncthreads();
        As[lkq + 0][lrow] = (float)hv[0];
        As[lkq + 1][lrow] = (float)hv[1];
        As[lkq + 2][lrow] = (float)hv[2];
        As[lkq + 3][lrow] = (float)hv[3];
        *(float4*)(&Bs[bkr][bcol]) = b4;
        __syncthreads();
        #pragma unroll
        for (int k = 0; k < 16; ++k) {
            float4 av = *(const float4*)(&As[k][ty << 2]);
            float4 bv = *(const float4*)(&Bs[k][tx << 2]);
            acc[0][0] = fmaf(av.x, bv.x, acc[0][0]);
            acc[0][1] = fmaf(av.x, bv.y, acc[0][1]);
            acc[0][2] = fmaf(av.x, bv.z, acc[0][2]);
            acc[0][3] = fmaf(av.x, bv.w, acc[0][3]);
            acc[1][0] = fmaf(av.y, bv.x, acc[1][0]);
            acc[1][1] = fmaf(av.y, bv.y, acc[1][1]);
            acc[1][2] = fmaf(av.y, bv.z, acc[1][2]);
            acc[1][3] = fmaf(av.y, bv.w, acc[1][3]);
            acc[2][0] = fmaf(av.z, bv.x, acc[2][0]);
            acc[2][1] = fmaf(av.z, bv.y, acc[2][1]);
            acc[2][2] = fmaf(av.z, bv.z, acc[2][2]);
            acc[2][3] = fmaf(av.z, bv.w, acc[2][3]);
            acc[3][0] = fmaf(av.w, bv.x, acc[3][0]);
            acc[3][1] = fmaf(av.w, bv.y, acc[3][1]);
            acc[3][2] = fmaf(av.w, bv.z, acc[3][2]);
            acc[3][3] = fmaf(av.w, bv.w, acc[3][3]);
        }
    }

    float4 bv4 = *(const float4*)(bm1 + (tx << 2));
    #pragma unroll
    for (int i = 0; i < 4; ++i) {
        float4 o;
        o.x = fmaxf(acc[i][0] + bv4.x, 0.f);
        o.y = fmaxf(acc[i][1] + bv4.y, 0.f);
        o.z = fmaxf(acc[i][2] + bv4.z, 0.f);
        o.w = fmaxf(acc[i][3] + bv4.w, 0.f);
        *(float4*)(&Hs[(ty << 2) + i][tx << 2]) = o;
    }
    __syncthreads();

    int r = t >> 2;
    int cg = (t & 3) << 2;
    float4 o2 = make_float4(0.f, 0.f, 0.f, 0.f);
    #pragma unroll 8
    for (int k = 0; k < D_FEAT; ++k) {
        float hk = Hs[r][k];
        float4 w4 = *(const float4*)(Wm2 + k * 16 + cg);
        o2.x = fmaf(hk, w4.x, o2.x);
        o2.y = fmaf(hk, w4.y, o2.y);
        o2.z = fmaf(hk, w4.z, o2.z);
        o2.w = fmaf(hk, w4.w, o2.w);
    }
    int gr = row0 + r;
    if (gr < N) {
        float4 b2 = *(const float4*)(bm2 + cg);
        float4 o;
        o.x = fmaxf(o2.x + b2.x, 0.f);
        o.y = fmaxf(o2.y + b2.y, 0.f);
        o.z = fmaxf(o2.z + b2.z, 0.f);
        o.w = fmaxf(o2.w + b2.w, 0.f);
        *(float4*)(out + (size_t)gr * 16 + cg) = o;
    }
}

extern "C" void kernel_launch(void* const* d_in, const int* in_sizes, int n_in,
                              void* d_out, int out_size, void* d_ws, size_t ws_size,
                              hipStream_t stream)
{
    const float* x     = (const float*)d_in[0];
    const int*   eidx  = (const int*)d_in[1];
    const float* attr  = (const float*)d_in[2];
    const float* W1    = (const float*)d_in[3];
    const float* root1 = (const float*)d_in[4];
    const float* b1    = (const float*)d_in[5];
    const float* W2    = (const float*)d_in[6];
    const float* root2 = (const float*)d_in[7];
    const float* b2    = (const float*)d_in[8];
    const float* Wm1   = (const float*)d_in[9];
    const float* bm1   = (const float*)d_in[10];
    const float* Wm2   = (const float*)d_in[11];
    const float* bm2   = (const float*)d_in[12];
    float* out = (float*)d_out;

    int N = in_sizes[0] / D_FEAT;
    int E = in_sizes[1] / 2;
    const int* esrc = eidx;
    const int* edst = eidx + E;
    int NBUCKET = (N + 127) >> 7;
    int chunk = (E + PART_B - 1) / PART_B;
    int L = NBUCKET * PART_B;
    int nbL = (L + 255) / 256;

    _Float16* agg = (_Float16*)d_ws;
    _Float16* h   = agg + (size_t)N * 5 * D_FEAT;
    _Float16* xh  = h + (size_t)N * D_FEAT;
    int2* packed  = (int2*)(xh + (size_t)N * D_FEAT);
    int2* staging = packed + E;
    _Float16* Wt1 = (_Float16*)(staging + E);
    _Float16* Wt2 = Wt1 + 64 * 256;
    unsigned int* counts  = (unsigned int*)(Wt2 + 64 * 384);
    unsigned int* partial = counts + L;
    unsigned int* rowptr  = partial + 512;

    dim3 blk(256);
    dim3 grid_w((N + 3) / 4);
    dim3 grid_g64((N + 63) / 64);
    dim3 grid_g128((N + 127) / 128);

    // atomic-free CSR build
    count_k<<<dim3(PART_B), blk, 0, stream>>>(edst, counts, E, chunk, NBUCKET);
    psum_k<<<dim3(nbL), blk, 0, stream>>>(counts, partial, L);
    pscan_k<<<1, 512, 0, stream>>>(partial, nbL);
    pwrite_k<<<dim3(nbL), blk, 0, stream>>>(counts, partial, L);
    place_k<<<dim3(PART_B), blk, 0, stream>>>(esrc, edst, attr, counts, staging, E, chunk, NBUCKET);
    binsort_k<<<dim3(NBUCKET), blk, 0, stream>>>(staging, counts, rowptr, packed, N, E, NBUCKET);

    // fp16 prep
    cvt_x_k<<<dim3((N * D_FEAT / 4 + 255) / 256), blk, 0, stream>>>(x, xh, N * D_FEAT / 4);
    prep_w_k<<<dim3(160), blk, 0, stream>>>(W1, root1, W2, root2, Wt1, Wt2);

    // conv1: K=3
    gather_k<3><<<grid_w, blk, 0, stream>>>(xh, packed, rowptr, agg, N);
    gemm_mfma<<<grid_g128, blk, 0, stream>>>(agg, 3 * D_FEAT, xh, Wt1, b1, h, N);

    // conv2: K=5 (gemm reads/writes h in place — per-block row ownership)
    gather_k<5><<<grid_w, blk, 0, stream>>>(h, packed, rowptr, agg, N);
    gemm_mfma<<<grid_g128, blk, 0, stream>>>(agg, 5 * D_FEAT, h, Wt2, b2, h, N);

    // MLP head
    mlp_tile<<<grid_g64, blk, 0, stream>>>(h, Wm1, bm1, Wm2, bm2, out, N);
}